// Round 1
// baseline (436.597 us; speedup 1.0000x reference)
//
#include <hip/hip_runtime.h>
#include <stdint.h>

typedef __attribute__((ext_vector_type(8))) short short8;
typedef __attribute__((ext_vector_type(4))) float f32x4;
typedef __attribute__((ext_vector_type(4))) unsigned short us4;

#define DI __device__ __forceinline__

static constexpr int Dm = 1024;   // hidden dim
static constexpr int Sm = 4096;   // latent tokens
static constexpr int Em = 160;    // encoder tokens
static constexpr int Hm = 16;     // heads

// workspace layout (bytes)
static constexpr size_t OFF_HSB  = 0;           // hs bf16 [8*4096][1024]  (later reused as attn-out bf16)
static constexpr size_t OFF_WT   = 67108864;    // 4x Wt bf16 [1024][1024] (transposed: [N][K])
static constexpr size_t OFF_QB   = 75497472;    // Q bf16 [8*4096][1024]
static constexpr size_t OFF_KB   = 142606336;   // K bf16 [8*160][1024]
static constexpr size_t OFF_VB   = 145227776;   // V bf16 [8*160][1024]
static constexpr size_t OFF_VT   = 147849216;   // V^T bf16 [8][16][64][192]
static constexpr size_t OFF_EHSB = 150994944;   // ehs bf16 [8*160][1024]

DI unsigned short f2b(float f) {
  union { float f; unsigned u; } x; x.f = f;
  unsigned r = x.u + 0x7fffu + ((x.u >> 16) & 1u);
  return (unsigned short)(r >> 16);
}

DI void gl_lds16(const void* g, void* l) {
  __builtin_amdgcn_global_load_lds(
      (const __attribute__((address_space(1))) unsigned int*)g,
      (__attribute__((address_space(3))) unsigned int*)l, 16, 0, 0);
}

// ---------------- fp32 -> bf16 convert (vectorized, grid-stride) ----------------
__global__ void k_cvt(const float* __restrict__ in, unsigned short* __restrict__ out, int n4) {
  int stride = gridDim.x * blockDim.x;
  for (int i = blockIdx.x * blockDim.x + threadIdx.x; i < n4; i += stride) {
    float4 v = ((const float4*)in)[i];
    us4 o = { f2b(v.x), f2b(v.y), f2b(v.z), f2b(v.w) };
    *(us4*)(out + (size_t)i * 4) = o;
  }
}

// ---------------- W [K][N] fp32 -> Wt [N][K] bf16 (tiled transpose) ----------------
__global__ void k_wtrans(const float* __restrict__ W0, const float* __restrict__ W1,
                         const float* __restrict__ W2, const float* __restrict__ W3,
                         unsigned short* __restrict__ Wt) {
  __shared__ float t[32][33];
  const float* W = (blockIdx.z == 0) ? W0 : (blockIdx.z == 1) ? W1 : (blockIdx.z == 2) ? W2 : W3;
  unsigned short* o = Wt + (size_t)blockIdx.z * 1048576;
  int tx = threadIdx.x, ty = threadIdx.y;
  int n = blockIdx.x * 32 + tx;
  int k0 = blockIdx.y * 32;
  #pragma unroll
  for (int j = ty; j < 32; j += 8) t[j][tx] = W[(size_t)(k0 + j) * 1024 + n];
  __syncthreads();
  #pragma unroll
  for (int j = ty; j < 32; j += 8)
    o[(size_t)(blockIdx.x * 32 + j) * 1024 + k0 + tx] = f2b(t[tx][j]);
}

// ---------------- bf16 GEMM: C[M,1024] = A[M,1024] @ Bt[1024,1024]^T ----------------
// 128x128 tile, BK=64, global_load_lds(16B), XOR-swizzled LDS, 2-barrier loop.
// MODE 0: write bf16 C.  MODE 1: write fp32 C + bias[n] + resid[m][n].
template<int MODE>
__global__ __launch_bounds__(256, 2) void k_gemm(const unsigned short* __restrict__ A,
                                                 const unsigned short* __restrict__ Bt,
                                                 void* __restrict__ Cout,
                                                 const float* __restrict__ bias,
                                                 const float* __restrict__ resid) {
  __shared__ __align__(16) char smem[32768];
  char* As = smem;
  char* Bs = smem + 16384;
  const int tid = threadIdx.x;
  const int lane = tid & 63;
  const int l15 = lane & 15;
  const int g = lane >> 4;
  const int wv = tid >> 6;
  const int wr = wv >> 1, wc = wv & 1;
  const int m0 = blockIdx.x * 128, n0 = blockIdx.y * 128;

  f32x4 acc[4][4];
  #pragma unroll
  for (int i = 0; i < 4; ++i)
    #pragma unroll
    for (int j = 0; j < 4; ++j) acc[i][j] = (f32x4){0.f, 0.f, 0.f, 0.f};

  for (int t = 0; t < 16; ++t) {
    __syncthreads();
    #pragma unroll
    for (int is = 0; is < 4; ++is) {
      int ch = is * 256 + tid;
      int row = ch >> 3, j = ch & 7;
      int sj = (j ^ (row & 7)) * 8;
      gl_lds16(A  + (size_t)(m0 + row) * 1024 + t * 64 + sj, As + ch * 16);
      gl_lds16(Bt + (size_t)(n0 + row) * 1024 + t * 64 + sj, Bs + ch * 16);
    }
    __syncthreads();
    short8 af[2][4], bf[2][4];
    #pragma unroll
    for (int kk = 0; kk < 2; ++kk)
      #pragma unroll
      for (int mt = 0; mt < 4; ++mt) {
        af[kk][mt] = *(const short8*)(As + (wr * 64 + mt * 16 + l15) * 128 + ((kk * 64 + g * 16) ^ ((l15 & 7) << 4)));
        bf[kk][mt] = *(const short8*)(Bs + (wc * 64 + mt * 16 + l15) * 128 + ((kk * 64 + g * 16) ^ ((l15 & 7) << 4)));
      }
    #pragma unroll
    for (int kk = 0; kk < 2; ++kk)
      #pragma unroll
      for (int mt = 0; mt < 4; ++mt)
        #pragma unroll
        for (int nt = 0; nt < 4; ++nt)
          acc[mt][nt] = __builtin_amdgcn_mfma_f32_16x16x32_bf16(af[kk][mt], bf[kk][nt], acc[mt][nt], 0, 0, 0);
  }

  #pragma unroll
  for (int mt = 0; mt < 4; ++mt)
    #pragma unroll
    for (int nt = 0; nt < 4; ++nt)
      #pragma unroll
      for (int r = 0; r < 4; ++r) {
        size_t row = (size_t)(m0 + wr * 64 + mt * 16 + 4 * g + r);
        int col = n0 + wc * 64 + nt * 16 + l15;
        size_t idx = row * 1024 + col;
        if (MODE == 0) ((unsigned short*)Cout)[idx] = f2b(acc[mt][nt][r]);
        else           ((float*)Cout)[idx] = acc[mt][nt][r] + bias[col] + resid[idx];
      }
}

// ---------------- V [bc][e][D] bf16 -> V^T [bc][h][d][192] bf16 ----------------
__global__ void k_vtrans(const unsigned short* __restrict__ Vb, unsigned short* __restrict__ Vt) {
  int cidx = blockIdx.x * 256 + threadIdx.x;       // 8192 rows x 20 chunks
  int row = cidx / 20, jc = cidx - row * 20;
  int bc = row >> 10, h = (row >> 6) & 15, d = row & 63;
  short8 o;
  #pragma unroll
  for (int i = 0; i < 8; ++i)
    o[i] = (short)Vb[((size_t)bc * Em + jc * 8 + i) * Dm + h * 64 + d];
  *(short8*)(Vt + (size_t)row * 192 + jc * 8) = o;
}

// ---------------- fused decomposing attention ----------------
// grid (S/64, H, B=2); block 256 = 4 waves; wave w = component c (bc = c*2 + b).
__global__ __launch_bounds__(256, 1) void k_attn(const unsigned short* __restrict__ Qb,
                                                 const unsigned short* __restrict__ Kb,
                                                 const unsigned short* __restrict__ Vt,
                                                 unsigned short* __restrict__ AOb) {
  __shared__ __align__(16) char smem[153600];
  char* KV = smem;                       // 98304: K [4][160][128B] swz, then V^T [4][64][384B] swz
  char* Qs = smem + 98304;               // 32768: Q [4][64][128B] swz
  char* Ps = smem + 131072;              // 21504: per-wave P [16][336B]
  float* pooled = (float*)(smem + 152576);  // [4 strips][16 rows][4 comps]

  const int tid = threadIdx.x, lane = tid & 63, wv = tid >> 6;
  const int g = lane >> 4, l15 = lane & 15;
  const int s0 = blockIdx.x * 64;
  const int h = blockIdx.y;
  const int b = blockIdx.z;
  const float scale = 0.125f;

  // stage Q: rows = c*64 + s (128B each)
  #pragma unroll
  for (int is = 0; is < 8; ++is) {
    int ch = is * 256 + tid;
    int row = ch >> 3, j = ch & 7;
    int sj = (j ^ (row & 7)) * 8;
    int c = row >> 6, s = row & 63;
    gl_lds16(Qb + ((size_t)(c * 2 + b) * Sm + s0 + s) * Dm + h * 64 + sj, Qs + ch * 16);
  }
  // stage K: rows = c*160 + e (128B each)
  #pragma unroll
  for (int is = 0; is < 20; ++is) {
    int ch = is * 256 + tid;
    int row = ch >> 3, j = ch & 7;
    int sj = (j ^ (row & 7)) * 8;
    int c = row / 160, e = row - c * 160;
    gl_lds16(Kb + ((size_t)(c * 2 + b) * Em + e) * Dm + h * 64 + sj, KV + ch * 16);
  }
  __syncthreads();

  unsigned preg[4][20];  // packed bf16 P, 4 strips x (10 etiles x 2 row-pairs)

  // ---- phase 1: QK^T + component/row softmax per 16-row strip ----
  #pragma unroll
  for (int st = 0; st < 4; ++st) {
    short8 qf[2];
    #pragma unroll
    for (int kk = 0; kk < 2; ++kk)
      qf[kk] = *(const short8*)(Qs + (wv * 64 + st * 16 + l15) * 128 + ((kk * 64 + g * 16) ^ ((l15 & 7) << 4)));
    f32x4 sc[10];
    #pragma unroll
    for (int et = 0; et < 10; ++et) {
      sc[et] = (f32x4){0.f, 0.f, 0.f, 0.f};
      #pragma unroll
      for (int kk = 0; kk < 2; ++kk) {
        short8 kf = *(const short8*)(KV + (wv * 160 + et * 16 + l15) * 128 + ((kk * 64 + g * 16) ^ ((l15 & 7) << 4)));
        sc[et] = __builtin_amdgcn_mfma_f32_16x16x32_bf16(qf[kk], kf, sc[et], 0, 0, 0);
      }
    }
    // pooled mean over E (rows s = st*16 + 4g + r; cols spread over the 16 lanes of group g)
    #pragma unroll
    for (int r = 0; r < 4; ++r) {
      float v = 0.f;
      #pragma unroll
      for (int et = 0; et < 10; ++et) v += sc[et][r];
      v += __shfl_xor(v, 1); v += __shfl_xor(v, 2); v += __shfl_xor(v, 4); v += __shfl_xor(v, 8);
      if (l15 == 0) pooled[(st * 16 + 4 * g + r) * 4 + wv] = v * (scale / 160.f);
    }
    __syncthreads();
    #pragma unroll
    for (int r = 0; r < 4; ++r) {
      const float* pp = &pooled[(st * 16 + 4 * g + r) * 4];
      float p0 = pp[0], p1 = pp[1], p2 = pp[2], p3 = pp[3];
      float m3 = fmaxf(fmaxf(p0, p1), fmaxf(p2, p3));
      float ssum = __expf(p0 - m3) + __expf(p1 - m3) + __expf(p2 - m3) + __expf(p3 - m3);
      float mine = (wv == 0) ? p0 : (wv == 1) ? p1 : (wv == 2) ? p2 : p3;
      float wp = __expf(mine - m3) / ssum;
      // row softmax over E
      float mx = sc[0][r];
      #pragma unroll
      for (int et = 1; et < 10; ++et) mx = fmaxf(mx, sc[et][r]);
      mx = fmaxf(mx, __shfl_xor(mx, 1)); mx = fmaxf(mx, __shfl_xor(mx, 2));
      mx = fmaxf(mx, __shfl_xor(mx, 4)); mx = fmaxf(mx, __shfl_xor(mx, 8));
      float pv[10]; float rs = 0.f;
      #pragma unroll
      for (int et = 0; et < 10; ++et) { pv[et] = __expf((sc[et][r] - mx) * scale); rs += pv[et]; }
      rs += __shfl_xor(rs, 1); rs += __shfl_xor(rs, 2); rs += __shfl_xor(rs, 4); rs += __shfl_xor(rs, 8);
      float wf = wp / rs;
      #pragma unroll
      for (int et = 0; et < 10; ++et) {
        unsigned short hb = f2b(pv[et] * wf);
        if ((r & 1) == 0) preg[st][et * 2 + (r >> 1)] = hb;
        else              preg[st][et * 2 + (r >> 1)] |= ((unsigned)hb) << 16;
      }
    }
  }
  __syncthreads();  // all K/Q reads done

  // ---- phase 2: stage V^T over the K region: rows = c*64 + d (384B each, 24 chunks) ----
  #pragma unroll
  for (int is = 0; is < 24; ++is) {
    int ch = is * 256 + tid;
    int row = ch / 24, j = ch - row * 24;
    int sj = (j ^ (row & 7)) * 8;
    gl_lds16(Vt + (size_t)((((row >> 6) * 2 + b) * Hm + h) * 64 + (row & 63)) * 192 + sj, KV + ch * 16);
  }
  __syncthreads();

  // ---- phase 3: P @ V per strip ----
  char* Pw = Ps + wv * 5376;
  const int bc = wv * 2 + b;
  #pragma unroll
  for (int st = 0; st < 4; ++st) {
    #pragma unroll
    for (int et = 0; et < 10; ++et)
      #pragma unroll
      for (int hh = 0; hh < 2; ++hh) {
        unsigned pk = preg[st][et * 2 + hh];
        *(unsigned short*)(Pw + (4 * g + 2 * hh    ) * 336 + (et * 16 + l15) * 2) = (unsigned short)(pk & 0xffffu);
        *(unsigned short*)(Pw + (4 * g + 2 * hh + 1) * 336 + (et * 16 + l15) * 2) = (unsigned short)(pk >> 16);
      }
    __syncthreads();
    f32x4 oa[4];
    #pragma unroll
    for (int dt = 0; dt < 4; ++dt) oa[dt] = (f32x4){0.f, 0.f, 0.f, 0.f};
    #pragma unroll
    for (int k5 = 0; k5 < 5; ++k5) {
      short8 pf = *(const short8*)(Pw + l15 * 336 + k5 * 64 + g * 16);
      #pragma unroll
      for (int dt = 0; dt < 4; ++dt) {
        short8 vf = *(const short8*)(KV + (wv * 64 + dt * 16 + l15) * 384 + ((k5 * 64 + g * 16) ^ ((l15 & 7) << 4)));
        oa[dt] = __builtin_amdgcn_mfma_f32_16x16x32_bf16(pf, vf, oa[dt], 0, 0, 0);
      }
    }
    #pragma unroll
    for (int dt = 0; dt < 4; ++dt)
      #pragma unroll
      for (int r = 0; r < 4; ++r)
        AOb[((size_t)bc * Sm + s0 + st * 16 + 4 * g + r) * Dm + h * 64 + dt * 16 + l15] = f2b(oa[dt][r]);
  }
}

extern "C" void kernel_launch(void* const* d_in, const int* in_sizes, int n_in,
                              void* d_out, int out_size, void* d_ws, size_t ws_size,
                              hipStream_t stream) {
  const float* hs  = (const float*)d_in[0];
  const float* ehs = (const float*)d_in[1];
  const float* Wq  = (const float*)d_in[2];
  const float* Wk  = (const float*)d_in[3];
  const float* Wv  = (const float*)d_in[4];
  const float* Wo  = (const float*)d_in[5];
  const float* bo  = (const float*)d_in[6];
  char* ws = (char*)d_ws;
  unsigned short* hsb = (unsigned short*)(ws + OFF_HSB);   // also attn-out bf16
  unsigned short* wt  = (unsigned short*)(ws + OFF_WT);
  unsigned short* qb  = (unsigned short*)(ws + OFF_QB);
  unsigned short* kb  = (unsigned short*)(ws + OFF_KB);
  unsigned short* vb  = (unsigned short*)(ws + OFF_VB);
  unsigned short* vt  = (unsigned short*)(ws + OFF_VT);
  unsigned short* eb  = (unsigned short*)(ws + OFF_EHSB);

  hipLaunchKernelGGL(k_cvt, dim3(2048), dim3(256), 0, stream, hs, hsb, 8 * 4096 * 1024 / 4);
  hipLaunchKernelGGL(k_cvt, dim3(1280), dim3(256), 0, stream, ehs, eb, 8 * 160 * 1024 / 4);
  hipLaunchKernelGGL(k_wtrans, dim3(32, 32, 4), dim3(32, 8), 0, stream, Wq, Wk, Wv, Wo, wt);
  hipLaunchKernelGGL((k_gemm<0>), dim3(256, 8), dim3(256), 0, stream, hsb, wt, (void*)qb,
                     (const float*)nullptr, (const float*)nullptr);
  hipLaunchKernelGGL((k_gemm<0>), dim3(10, 8), dim3(256), 0, stream, eb, wt + 1048576, (void*)kb,
                     (const float*)nullptr, (const float*)nullptr);
  hipLaunchKernelGGL((k_gemm<0>), dim3(10, 8), dim3(256), 0, stream, eb, wt + 2 * 1048576, (void*)vb,
                     (const float*)nullptr, (const float*)nullptr);
  hipLaunchKernelGGL(k_vtrans, dim3(640), dim3(256), 0, stream, vb, vt);
  hipLaunchKernelGGL(k_attn, dim3(64, 16, 2), dim3(256), 0, stream, qb, kb, vt, hsb);
  hipLaunchKernelGGL((k_gemm<1>), dim3(256, 8), dim3(256), 0, stream, hsb, wt + 3 * 1048576, d_out, bo, hs);
}